// Round 3
// baseline (386.125 us; speedup 1.0000x reference)
//
#include <hip/hip_runtime.h>

// phi (B,2,H,W) f32 -> out (B,1,H,W) f32 ; splat ones with bilinear weights, wrap BC
constexpr int H = 2048;
constexpr int W = 2048;
constexpr int TH = 64, TW = 64;
constexpr int HALO = 8;                 // |phi|~N(0,1); max|z| over 33M draws ~5.7 << 8
constexpr int LH = TH + 2 * HALO;       // 80
constexpr int LW = TW + 2 * HALO;       // 80
constexpr int TILE_ELEMS = LH * LW;     // 6400
constexpr int TR = H / TH;              // 32
constexpr int TC = W / TW;              // 32

// ---------------- Pass 1: splat into LDS tile, dump tile to workspace ----------------
__global__ __launch_bounds__(256)
void splat_pass1(const float* __restrict__ phi, float* __restrict__ wsTiles,
                 int* __restrict__ flag, float* __restrict__ out) {
    __shared__ float tile[TILE_ELEMS];   // 25.6 KB

    const int tilesPerImg = TR * TC;     // 1024
    int id = blockIdx.x;
    int b  = id / tilesPerImg;
    int t  = id - b * tilesPerImg;
    int ti = t / TC;
    int tj = t - ti * TC;
    int i0 = ti * TH;
    int j0 = tj * TW;

    for (int k = threadIdx.x; k < TILE_ELEMS; k += 256) tile[k] = 0.0f;
    __syncthreads();

    const float* phiB = phi + (size_t)b * 2 * H * W;
    float* outb = out + (size_t)b * H * W;

    #pragma unroll
    for (int qq = 0; qq < 4; ++qq) {
        int q  = threadIdx.x + qq * 256;
        int r  = q >> 4;
        int c4 = (q & 15) << 2;
        int i  = i0 + r;
        int j  = j0 + c4;
        const float4 p0 = *reinterpret_cast<const float4*>(phiB + (size_t)i * W + j);
        const float4 p1 = *reinterpret_cast<const float4*>(phiB + (size_t)H * W + (size_t)i * W + j);
        const float pxs[4] = {p0.x, p0.y, p0.z, p0.w};
        const float pys[4] = {p1.x, p1.y, p1.z, p1.w};

        #pragma unroll
        for (int e = 0; e < 4; ++e) {
            float x = (float)i + pxs[e];
            float y = (float)(j + e) + pys[e];
            float x0f = floorf(x), y0f = floorf(y);
            float wx1 = x - x0f, wy1 = y - y0f;
            float wx0 = 1.0f - wx1, wy0 = 1.0f - wy1;
            int ix0 = (int)x0f;
            int iy0 = (int)y0f;
            int lx = ix0 - (i0 - HALO);
            int ly = iy0 - (j0 - HALO);
            if ((unsigned)lx < (unsigned)(LH - 1) && (unsigned)ly < (unsigned)(LW - 1)) {
                float* base = tile + lx * LW + ly;
                atomicAdd(base,          wx0 * wy0);
                atomicAdd(base + 1,      wx0 * wy1);
                atomicAdd(base + LW,     wx1 * wy0);
                atomicAdd(base + LW + 1, wx1 * wy1);
            } else {
                // statistically never for N(0,1); correctness for any input
                atomicExch(flag, 1);
                int gx0 = ix0 % H; if (gx0 < 0) gx0 += H;
                int gy0 = iy0 % W; if (gy0 < 0) gy0 += W;
                int gx1 = gx0 + 1; if (gx1 == H) gx1 = 0;
                int gy1 = gy0 + 1; if (gy1 == W) gy1 = 0;
                atomicAdd(outb + (size_t)gx0 * W + gy0, wx0 * wy0);
                atomicAdd(outb + (size_t)gx0 * W + gy1, wx0 * wy1);
                atomicAdd(outb + (size_t)gx1 * W + gy0, wx1 * wy0);
                atomicAdd(outb + (size_t)gx1 * W + gy1, wx1 * wy1);
            }
        }
    }
    __syncthreads();

    // dump whole tile (zeros included) to ws with vectorized plain stores
    float* wtile = wsTiles + (size_t)id * TILE_ELEMS;
    for (int k4 = threadIdx.x; k4 < TILE_ELEMS / 4; k4 += 256) {
        float4 v = *reinterpret_cast<const float4*>(tile + 4 * k4);
        *reinterpret_cast<float4*>(wtile + 4 * k4) = v;
    }
}

// ---------------- Pass 2: gather 1-4 ws cells per output pixel ----------------
__global__ __launch_bounds__(256)
void gather_pass2(const float* __restrict__ wsTiles, const int* __restrict__ flag,
                  float* __restrict__ out) {
    int tid = blockIdx.x * 256 + threadIdx.x;
    int q     = tid & 511;          // quad within row (W/4 = 512)
    int rowId = tid >> 9;           // b*H + r
    int b = rowId >> 11;            // H = 2048
    int r = rowId & 2047;
    int c4 = q << 2;

    int ti = r >> 6,  rl = r & 63;
    int tj = c4 >> 6, cl = c4 & 63;

    // row candidates (tile index, local row)
    int rt0 = ti, lr0 = rl + HALO;
    int nrow = 1, rt1 = 0, lr1 = 0;
    if (rl < HALO)            { rt1 = (ti + TR - 1) & (TR - 1); lr1 = rl + TH + HALO; nrow = 2; }
    else if (rl >= TH - HALO) { rt1 = (ti + 1) & (TR - 1);      lr1 = rl - (TH - HALO); nrow = 2; }

    // col candidates — uniform for all 4 pixels of the quad (cl % 4 == 0, cl+3 <= 63)
    int ct0 = tj, lc0 = cl + HALO;
    int ncol = 1, ct1 = 0, lc1 = 0;
    if (cl < HALO)            { ct1 = (tj + TC - 1) & (TC - 1); lc1 = cl + TW + HALO; ncol = 2; }
    else if (cl >= TW - HALO) { ct1 = (tj + 1) & (TC - 1);      lc1 = cl - (TW - HALO); ncol = 2; }

    const size_t tb = (size_t)b * (TR * TC);
    float4 s = make_float4(0.f, 0.f, 0.f, 0.f);

    auto acc = [&](int tr_, int tc_, int lr_, int lc_) {
        const float4 v = *reinterpret_cast<const float4*>(
            wsTiles + ((tb + (size_t)tr_ * TC + tc_) * TILE_ELEMS + (size_t)lr_ * LW + lc_));
        s.x += v.x; s.y += v.y; s.z += v.z; s.w += v.w;
    };

    acc(rt0, ct0, lr0, lc0);
    if (ncol == 2) acc(rt0, ct1, lr0, lc1);
    if (nrow == 2) {
        acc(rt1, ct0, lr1, lc0);
        if (ncol == 2) acc(rt1, ct1, lr1, lc1);
    }

    size_t oidx = ((size_t)b * H + r) * W + c4;
    if (*flag) {  // fallback atomics landed in out (never for this input); keep them
        const float4 ov = *reinterpret_cast<const float4*>(out + oidx);
        s.x += ov.x; s.y += ov.y; s.z += ov.z; s.w += ov.w;
    }
    *reinterpret_cast<float4*>(out + oidx) = s;
}

// ---------------- Fallback (ws too small): R2 single-pass atomic-flush kernel ----------------
__global__ __launch_bounds__(256)
void splat_tile_atomic(const float* __restrict__ phi, float* __restrict__ out) {
    __shared__ float tile[TILE_ELEMS];
    const int tilesPerImg = TR * TC;
    int id = blockIdx.x;
    int b  = id / tilesPerImg;
    int t  = id - b * tilesPerImg;
    int ti = t / TC;
    int tj = t - ti * TC;
    int i0 = ti * TH;
    int j0 = tj * TW;

    for (int k = threadIdx.x; k < TILE_ELEMS; k += 256) tile[k] = 0.0f;
    __syncthreads();

    const float* phiB = phi + (size_t)b * 2 * H * W;
    float* outb = out + (size_t)b * H * W;

    #pragma unroll
    for (int qq = 0; qq < 4; ++qq) {
        int q  = threadIdx.x + qq * 256;
        int r  = q >> 4;
        int c4 = (q & 15) << 2;
        int i  = i0 + r;
        int j  = j0 + c4;
        const float4 p0 = *reinterpret_cast<const float4*>(phiB + (size_t)i * W + j);
        const float4 p1 = *reinterpret_cast<const float4*>(phiB + (size_t)H * W + (size_t)i * W + j);
        const float pxs[4] = {p0.x, p0.y, p0.z, p0.w};
        const float pys[4] = {p1.x, p1.y, p1.z, p1.w};
        #pragma unroll
        for (int e = 0; e < 4; ++e) {
            float x = (float)i + pxs[e];
            float y = (float)(j + e) + pys[e];
            float x0f = floorf(x), y0f = floorf(y);
            float wx1 = x - x0f, wy1 = y - y0f;
            float wx0 = 1.0f - wx1, wy0 = 1.0f - wy1;
            int ix0 = (int)x0f, iy0 = (int)y0f;
            int lx = ix0 - (i0 - HALO);
            int ly = iy0 - (j0 - HALO);
            if ((unsigned)lx < (unsigned)(LH - 1) && (unsigned)ly < (unsigned)(LW - 1)) {
                float* base = tile + lx * LW + ly;
                atomicAdd(base,          wx0 * wy0);
                atomicAdd(base + 1,      wx0 * wy1);
                atomicAdd(base + LW,     wx1 * wy0);
                atomicAdd(base + LW + 1, wx1 * wy1);
            } else {
                int gx0 = ix0 % H; if (gx0 < 0) gx0 += H;
                int gy0 = iy0 % W; if (gy0 < 0) gy0 += W;
                int gx1 = gx0 + 1; if (gx1 == H) gx1 = 0;
                int gy1 = gy0 + 1; if (gy1 == W) gy1 = 0;
                atomicAdd(outb + (size_t)gx0 * W + gy0, wx0 * wy0);
                atomicAdd(outb + (size_t)gx0 * W + gy1, wx0 * wy1);
                atomicAdd(outb + (size_t)gx1 * W + gy0, wx1 * wy0);
                atomicAdd(outb + (size_t)gx1 * W + gy1, wx1 * wy1);
            }
        }
    }
    __syncthreads();

    for (int k = threadIdx.x; k < TILE_ELEMS; k += 256) {
        float v = tile[k];
        if (v != 0.0f) {
            int rr = k / LW;
            int cc = k - rr * LW;
            int gr = (i0 - HALO + rr) & (H - 1);
            int gc = (j0 - HALO + cc) & (W - 1);
            atomicAdd(outb + (size_t)gr * W + gc, v);
        }
    }
}

extern "C" void kernel_launch(void* const* d_in, const int* in_sizes, int n_in,
                              void* d_out, int out_size, void* d_ws, size_t ws_size,
                              hipStream_t stream) {
    const float* phi = (const float*)d_in[0];
    float* out = (float*)d_out;

    int B = out_size / (H * W);
    int nTiles = B * TR * TC;                                  // 4096
    size_t tilesBytes = (size_t)nTiles * TILE_ELEMS * sizeof(float);  // 104.86 MB
    size_t wsNeeded = tilesBytes + 16;

    hipMemsetAsync(out, 0, (size_t)out_size * sizeof(float), stream);

    if (ws_size >= wsNeeded) {
        float* wsTiles = (float*)d_ws;
        int* flag = (int*)((char*)d_ws + tilesBytes);
        hipMemsetAsync(flag, 0, sizeof(int), stream);
        splat_pass1<<<nTiles, 256, 0, stream>>>(phi, wsTiles, flag, out);
        int grid2 = out_size / 4 / 256;                        // 16384
        gather_pass2<<<grid2, 256, 0, stream>>>(wsTiles, flag, out);
    } else {
        splat_tile_atomic<<<nTiles, 256, 0, stream>>>(phi, out);
    }
}